// Round 2
// 504.380 us; speedup vs baseline: 1.0753x; 1.0753x over previous
//
#include <hip/hip_runtime.h>
#include <hip/hip_bf16.h>
#include <stdint.h>

using bf16 = __hip_bfloat16;
using bf16x8 = __attribute__((ext_vector_type(8))) short;   // 8 bf16 = 4 VGPRs
using f32x4  = __attribute__((ext_vector_type(4))) float;

#define AS1 __attribute__((address_space(1)))
#define AS3 __attribute__((address_space(3)))

__device__ __forceinline__ void async_ld16(const void* g, void* l) {
    __builtin_amdgcn_global_load_lds((const AS1 void*)g, (AS3 void*)l, 16, 0, 0);
}

__device__ __forceinline__ f32x4 mfma_bf16(bf16x8 a, bf16x8 b, f32x4 c) {
    return __builtin_amdgcn_mfma_f32_16x16x32_bf16(a, b, c, 0, 0, 0);
}

__device__ __forceinline__ float sexp(float x) {
    return __expf(fmaxf(x, -80.0f));
}

// ---- 16-lane-group reductions: DPP row_shr (VALU) + one broadcast swizzle ----
template<int N> __device__ __forceinline__ float dpp_max16(float x) {
    int xi = __builtin_bit_cast(int, x);
    int yi = __builtin_amdgcn_update_dpp(xi, xi, 0x110 | N, 0xf, 0xf, false);
    return fmaxf(x, __builtin_bit_cast(float, yi));
}
template<int N> __device__ __forceinline__ float dpp_add16(float x) {
    int xi = __builtin_bit_cast(int, x);
    int yi = __builtin_amdgcn_update_dpp(0, xi, 0x110 | N, 0xf, 0xf, true);
    return x + __builtin_bit_cast(float, yi);
}
__device__ __forceinline__ float bcast15(float x) {
    return __builtin_bit_cast(float,
        __builtin_amdgcn_ds_swizzle(__builtin_bit_cast(int, x), 0x01F0));
}
__device__ __forceinline__ float redmax16(float x) {
    x = dpp_max16<1>(x); x = dpp_max16<2>(x);
    x = dpp_max16<4>(x); x = dpp_max16<8>(x);
    return bcast15(x);
}
__device__ __forceinline__ float redsum16(float x) {
    x = dpp_add16<1>(x); x = dpp_add16<2>(x);
    x = dpp_add16<4>(x); x = dpp_add16<8>(x);
    return bcast15(x);
}

// ---------------------------------------------------------------------------
// Merged f32->bf16 converts
// ---------------------------------------------------------------------------
__device__ __forceinline__ void cvt8(const float* p, bf16* d) {
    float4 lo = *(const float4*)p;
    float4 hi = *(const float4*)(p + 4);
    bf16 t8[8] = {__float2bfloat16(lo.x), __float2bfloat16(lo.y),
                  __float2bfloat16(lo.z), __float2bfloat16(lo.w),
                  __float2bfloat16(hi.x), __float2bfloat16(hi.y),
                  __float2bfloat16(hi.z), __float2bfloat16(hi.w)};
    *(bf16x8*)d = *(const bf16x8*)t8;
}

__global__ __launch_bounds__(256) void cvt4_k(const float* __restrict__ x,  bf16* __restrict__ xb,
                                              const float* __restrict__ wq, bf16* __restrict__ wqb,
                                              const float* __restrict__ wk, bf16* __restrict__ wkb,
                                              const float* __restrict__ wv, bf16* __restrict__ wvb) {
    int stride = gridDim.x * blockDim.x;
    for (int u = blockIdx.x * blockDim.x + threadIdx.x; u < 4194304; u += stride) {
        const float* s; bf16* d; size_t off;
        if (u < 1048576)      { s = x;  d = xb;  off = (size_t)u * 8; }
        else if (u < 3145728) { s = wq; d = wqb; off = (size_t)(u - 1048576) * 8; }
        else if (u < 3670016) { s = wk; d = wkb; off = (size_t)(u - 3145728) * 8; }
        else                  { s = wv; d = wvb; off = (size_t)(u - 3670016) * 8; }
        cvt8(s + off, d + off);
    }
}

__global__ __launch_bounds__(256) void cvt_f32_bf16(const float* __restrict__ src,
                                                    bf16* __restrict__ dst, int n8) {
    int stride = gridDim.x * blockDim.x;
    for (int u = blockIdx.x * blockDim.x + threadIdx.x; u < n8; u += stride)
        cvt8(src + (size_t)u * 8, dst + (size_t)u * 8);
}

// ---------------------------------------------------------------------------
// OLD simple GEMM (kept only for the no-workspace fallback, f32 sources).
// ---------------------------------------------------------------------------
template<bool SRCF32>
__device__ __forceinline__ void stage_tile(const void* __restrict__ src,
                                           bf16* __restrict__ s,
                                           int row0, int K, int k0, int tid) {
    if constexpr (SRCF32) {
        const float* g = (const float*)src;
        #pragma unroll
        for (int i = 0; i < 2; ++i) {
            int u = tid + 256 * i;
            int row = u >> 2, c8 = (u & 3) * 8;
            cvt8(g + (size_t)(row0 + row) * K + k0 + c8, &s[row * 32 + c8]);
        }
    } else {
        const bf16* g = (const bf16*)src;
        const int wave = tid >> 6, lane = tid & 63;
        const int c0 = wave * 64 + lane;
        const int r0 = c0 >> 2, cb0 = (c0 & 3) * 16;
        const int c1 = 256 + c0;
        const int r1 = c1 >> 2, cb1 = (c1 & 3) * 16;
        async_ld16((const char*)(g + (size_t)(row0 + r0) * K + k0) + cb0,
                   (char*)s + wave * 1024);
        async_ld16((const char*)(g + (size_t)(row0 + r1) * K + k0) + cb1,
                   (char*)s + 4096 + wave * 1024);
    }
}

template<bool AF32, bool BF32, int MODE>
__global__ __launch_bounds__(256) void gemm_bt(const void* __restrict__ A,
                                               const void* __restrict__ B,
                                               void* __restrict__ C,
                                               bf16* __restrict__ Qp,
                                               bf16* __restrict__ Kp,
                                               bf16* __restrict__ Vp,
                                               int M, int N, int K) {
    __shared__ bf16 sA[128 * 32];
    __shared__ bf16 sB[128 * 32];
    const int tid  = threadIdx.x;
    const int lane = tid & 63;
    const int wave = tid >> 6;
    const int m0 = blockIdx.y * 128;
    const int n0 = blockIdx.x * 128;
    const int mrow = (wave >> 1) * 64;
    const int ncol = (wave & 1) * 64;

    f32x4 acc[4][4] = {};

    for (int k0 = 0; k0 < K; k0 += 32) {
        __syncthreads();
        stage_tile<AF32>(A, sA, m0, K, k0, tid);
        stage_tile<BF32>(B, sB, n0, K, k0, tid);
        __syncthreads();

        bf16x8 af[4], bfr[4];
        #pragma unroll
        for (int i = 0; i < 4; ++i)
            af[i] = *(const bf16x8*)&sA[(mrow + i * 16 + (lane & 15)) * 32 + (lane >> 4) * 8];
        #pragma unroll
        for (int j = 0; j < 4; ++j)
            bfr[j] = *(const bf16x8*)&sB[(ncol + j * 16 + (lane & 15)) * 32 + (lane >> 4) * 8];
        #pragma unroll
        for (int i = 0; i < 4; ++i)
            #pragma unroll
            for (int j = 0; j < 4; ++j)
                acc[i][j] = mfma_bf16(af[i], bfr[j], acc[i][j]);
    }

    #pragma unroll
    for (int i = 0; i < 4; ++i)
        #pragma unroll
        for (int j = 0; j < 4; ++j)
            #pragma unroll
            for (int r = 0; r < 4; ++r) {
                int row = m0 + mrow + i * 16 + (lane >> 4) * 4 + r;
                int col = n0 + ncol + j * 16 + (lane & 15);
                float fv = acc[i][j][r];
                if constexpr (MODE == 0) {
                    ((bf16*)C)[(size_t)row * N + col] = __float2bfloat16(fv);
                } else if constexpr (MODE == 1) {
                    ((bf16*)C)[(size_t)col * M + row] = __float2bfloat16(fv);
                } else if constexpr (MODE == 2) {
                    bf16 v = __float2bfloat16(fv);
                    if (col < 4096)      Qp[(size_t)row * 4096 + col] = v;
                    else if (col < 5120) Kp[(size_t)row * 1024 + (col - 4096)] = v;
                    else                 Vp[(size_t)(col - 5120) * 2048 + row] = v;
                } else {
                    ((float*)C)[(size_t)row * N + col] = fv;
                }
            }
}

// ---------------------------------------------------------------------------
// Pipelined GEMM: C = A[M,K] @ B[N,K]^T, bf16 sources, 128x128 tile,
// BK=32, 4 waves. Ring of 4 LDS slots, depth-3 prefetch via global_load_lds,
// counted s_waitcnt vmcnt(8) (never 0 in-loop), raw s_barrier, both-sides
// 16B-slot XOR swizzle (kills the 8-way bank conflict), setprio around MFMA.
// Requires K % 128 == 0 (K=4096 here).
// MODE 2: QKV route. MODE 3: C f32 row-major.
// ---------------------------------------------------------------------------
template<int MODE>
__global__ __launch_bounds__(256, 2) void gemm_bt_p(const bf16* __restrict__ A,
                                                    const bf16* __restrict__ B,
                                                    void* __restrict__ C,
                                                    bf16* __restrict__ Qp,
                                                    bf16* __restrict__ Kp,
                                                    bf16* __restrict__ Vp,
                                                    int M, int N, int K) {
    // 4 distinct arrays (not one ring array): lets the waitcnt pass
    // alias-disambiguate LDS-DMA writes vs fragment ds_reads.
    __shared__ __align__(16) bf16 s0[8192];   // A: [0,4096), B: [4096,8192)
    __shared__ __align__(16) bf16 s1[8192];
    __shared__ __align__(16) bf16 s2[8192];
    __shared__ __align__(16) bf16 s3[8192];

    const int tid  = threadIdx.x;
    const int lane = tid & 63;
    const int wave = tid >> 6;
    const int m0 = blockIdx.y * 128;
    const int n0 = blockIdx.x * 128;
    const int mrow = (wave >> 1) * 64;
    const int ncol = (wave & 1) * 64;
    const int NT = K >> 5;

    // Swizzled fragment LDS offsets (loop-invariant). Logical 16B slot q is
    // stored at physical slot q ^ ((row>>1)&3): spreads the 16 lanes of each
    // quarter over 8 distinct 128B periods -> 2-way (free) instead of 8-way.
    int offA[4], offB[4];
    {
        const int q = lane >> 4;
        #pragma unroll
        for (int i = 0; i < 4; ++i) {
            const int ra = mrow + i * 16 + (lane & 15);
            offA[i] = ra * 32 + ((q ^ ((ra >> 1) & 3)) * 8);
            const int rb = ncol + i * 16 + (lane & 15);
            offB[i] = rb * 32 + ((q ^ ((rb >> 1) & 3)) * 8);
        }
    }

    // Staging: LDS dest stays linear (global_load_lds writes base+lane*16);
    // the swizzle is applied by permuting the per-lane GLOBAL source slot.
    // Coalescing preserved: 4 lanes of a row still cover the same 64B segment.
    const int u0  = wave * 64 + lane, u1 = u0 + 256;
    const int rA0 = u0 >> 2, q0 = (u0 & 3) ^ ((rA0 >> 1) & 3);
    const int rA1 = u1 >> 2, q1 = (u1 & 3) ^ ((rA1 >> 1) & 3);
    const bf16* gA0 = A + (size_t)(m0 + rA0) * K + q0 * 8;
    const bf16* gA1 = A + (size_t)(m0 + rA1) * K + q1 * 8;
    const bf16* gB0 = B + (size_t)(n0 + rA0) * K + q0 * 8;
    const bf16* gB1 = B + (size_t)(n0 + rA1) * K + q1 * 8;
    const int d0 = wave * 512;          // wave-uniform LDS elem offsets
    const int d1 = 2048 + wave * 512;

    auto stage = [&](bf16* dst, int k0) __attribute__((always_inline)) {
        async_ld16(gA0 + k0, dst + d0);
        async_ld16(gA1 + k0, dst + d1);
        async_ld16(gB0 + k0, dst + 4096 + d0);
        async_ld16(gB1 + k0, dst + 4096 + d1);
    };

    f32x4 acc[4][4] = {};

    // Prologue: tiles 0,1,2 in flight (12 loads); wait tile 0 (leave 8).
    stage(s0, 0);
    stage(s1, 32);
    stage(s2, 64);
    asm volatile("s_waitcnt vmcnt(8)" ::: "memory");
    __builtin_amdgcn_s_barrier();
    asm volatile("" ::: "memory");
    __builtin_amdgcn_sched_barrier(0);

    // Tile t: read slot t&3, stage tile t+3 into slot (t+3)&3 (== slot t-1,
    // fully consumed last tile -> no read/write overlap by construction).
    // End-of-tile: 12 loads outstanding, vmcnt(8) -> tile t+1 has landed.
    auto body = [&](const bf16* sCur, bf16* sNxt, int t) __attribute__((always_inline)) {
        bf16x8 af[4], bfr[4];
        #pragma unroll
        for (int i = 0; i < 4; ++i) af[i]  = *(const bf16x8*)(sCur + offA[i]);
        #pragma unroll
        for (int j = 0; j < 4; ++j) bfr[j] = *(const bf16x8*)(sCur + 4096 + offB[j]);
        const int k3 = (t + 3 < NT) ? (t + 3) * 32 : 0;   // tail: stage junk into dead slot
        stage(sNxt, k3);
        __builtin_amdgcn_s_setprio(1);
        #pragma unroll
        for (int i = 0; i < 4; ++i)
            #pragma unroll
            for (int j = 0; j < 4; ++j)
                acc[i][j] = mfma_bf16(af[i], bfr[j], acc[i][j]);
        __builtin_amdgcn_s_setprio(0);
        __builtin_amdgcn_sched_barrier(0);
        asm volatile("s_waitcnt vmcnt(8) lgkmcnt(0)" ::: "memory");
        __builtin_amdgcn_s_barrier();
        asm volatile("" ::: "memory");
        __builtin_amdgcn_sched_barrier(0);
    };

    for (int t = 0; t < NT; t += 4) {
        body(s0, s3, t);
        body(s1, s0, t + 1);
        body(s2, s1, t + 2);
        body(s3, s2, t + 3);
    }
    // Drain LDS-DMA before the wave can exit (LDS may be reassigned).
    asm volatile("s_waitcnt vmcnt(0)" ::: "memory");

    #pragma unroll
    for (int i = 0; i < 4; ++i)
        #pragma unroll
        for (int j = 0; j < 4; ++j)
            #pragma unroll
            for (int r = 0; r < 4; ++r) {
                int row = m0 + mrow + i * 16 + (lane >> 4) * 4 + r;
                int col = n0 + ncol + j * 16 + (lane & 15);
                float fv = acc[i][j][r];
                if constexpr (MODE == 2) {
                    bf16 v = __float2bfloat16(fv);
                    if (col < 4096)      Qp[(size_t)row * 4096 + col] = v;
                    else if (col < 5120) Kp[(size_t)row * 1024 + (col - 4096)] = v;
                    else                 Vp[(size_t)(col - 5120) * 2048 + row] = v;
                } else {
                    ((float*)C)[(size_t)row * N + col] = fv;
                }
            }
}

// ---------------------------------------------------------------------------
// Merged RoPE: h<32 -> Q head h; h>=32 -> K head h-32. cos/sin f32 [T,64].
// ---------------------------------------------------------------------------
__global__ __launch_bounds__(256) void rope_all(bf16* __restrict__ Q,
                                                bf16* __restrict__ K,
                                                const float* __restrict__ cosp,
                                                const float* __restrict__ sinp,
                                                const int* __restrict__ spp) {
    int idx = blockIdx.x * blockDim.x + threadIdx.x;
    int d = idx & 63;
    int h = (idx >> 6) % 40;
    int t = idx / (64 * 40);
    int sp = *spp;
    float c = cosp[(size_t)(t + sp) * 64 + d];
    float s = sinp[(size_t)(t + sp) * 64 + d];
    bf16* row = (h < 32) ? (Q + (size_t)t * 4096 + h * 128)
                         : (K + (size_t)t * 1024 + (h - 32) * 128);
    float x1 = __bfloat162float(row[d]);
    float x2 = __bfloat162float(row[64 + d]);
    row[d]      = __float2bfloat16(x1 * c - x2 * s);
    row[64 + d] = __float2bfloat16(x2 * c + x1 * s);
}

// ---------------------------------------------------------------------------
// Flash attention, causal, T=2048, D=128, 32 Q heads, 8 KV heads (GQA 4:1).
// ---------------------------------------------------------------------------
#define NEG_SENT (-1.0e9f)
__global__ __launch_bounds__(256) void attn_k(const bf16* __restrict__ Q,
                                              const bf16* __restrict__ K,
                                              const bf16* __restrict__ VT,
                                              bf16* __restrict__ Y) {
    constexpr int SKS = 136;
    constexpr int SVS = 72;
    __shared__ bf16 sK[64 * SKS];    // 17408 B; P scratch aliases this
    __shared__ bf16 sVT[128 * SVS];  // 18432 B

    const int tid  = threadIdx.x;
    const int lane = tid & 63;
    const int wave = tid >> 6;
    const int qtile = 31 - (blockIdx.x >> 5);
    const int head  = blockIdx.x & 31;
    const int g     = head >> 2;
    const int qrow0 = qtile * 64 + wave * 16;
    bf16* sPw = sK + wave * 1152;

    bf16x8 qf[4];
    {
        const bf16* qbase = Q + (size_t)(qrow0 + (lane & 15)) * 4096 + head * 128;
        #pragma unroll
        for (int kk = 0; kk < 4; ++kk)
            qf[kk] = *(const bf16x8*)(qbase + kk * 32 + (lane >> 4) * 8);
    }

    float m_i[4], l_i[4];
    #pragma unroll
    for (int r = 0; r < 4; ++r) { m_i[r] = NEG_SENT; l_i[r] = 0.f; }
    f32x4 o[8] = {};
    const float scale = 0.08838834764831845f;

    for (int kt = 0; kt <= qtile; ++kt) {
        const int kt0 = kt * 64;
        __syncthreads();
        #pragma unroll
        for (int i = 0; i < 4; ++i) {
            int c = i * 256 + tid;
            {
                int row = c >> 4, ch = c & 15;
                *(uint4*)&sK[row * SKS + ch * 8] =
                    *(const uint4*)(K + (size_t)(kt0 + row) * 1024 + g * 128 + ch * 8);
            }
            {
                int row = c >> 3, ch = c & 7;
                *(uint4*)&sVT[row * SVS + ch * 8] =
                    *(const uint4*)(VT + (size_t)(g * 128 + row) * 2048 + kt0 + ch * 8);
            }
        }
        __syncthreads();

        f32x4 s[4];
        #pragma unroll
        for (int j = 0; j < 4; ++j) {
            f32x4 a = {};
            #pragma unroll
            for (int kk = 0; kk < 4; ++kk) {
                bf16x8 kfrag = *(const bf16x8*)&sK[(j * 16 + (lane & 15)) * SKS +
                                                   kk * 32 + (lane >> 4) * 8];
                a = mfma_bf16(qf[kk], kfrag, a);
            }
            s[j] = a;
        }

        #pragma unroll
        for (int j = 0; j < 4; ++j) {
            int tk = kt0 + j * 16 + (lane & 15);
            #pragma unroll
            for (int r = 0; r < 4; ++r) {
                int tq = qrow0 + (lane >> 4) * 4 + r;
                float v = s[j][r] * scale;
                s[j][r] = (tk > tq) ? NEG_SENT : v;
            }
        }

        #pragma unroll
        for (int r = 0; r < 4; ++r) {
            float mx = fmaxf(fmaxf(s[0][r], s[1][r]), fmaxf(s[2][r], s[3][r]));
            mx = redmax16(mx);
            float mn = fmaxf(m_i[r], mx);
            float alpha = sexp(m_i[r] - mn);
            m_i[r] = mn;
            float rs = 0.f;
            #pragma unroll
            for (int j = 0; j < 4; ++j) {
                float pv = sexp(s[j][r] - mn);
                s[j][r] = pv;
                rs += pv;
            }
            l_i[r] = l_i[r] * alpha + rs;
            #pragma unroll
            for (int j2 = 0; j2 < 8; ++j2) o[j2][r] *= alpha;
        }

        __syncthreads();

        #pragma unroll
        for (int j = 0; j < 4; ++j)
            #pragma unroll
            for (int r = 0; r < 4; ++r)
                sPw[((lane >> 4) * 4 + r) * SVS + j * 16 + (lane & 15)] =
                    __float2bfloat16(s[j][r]);
        __asm__ volatile("s_waitcnt lgkmcnt(0)" ::: "memory");

        #pragma unroll
        for (int kk2 = 0; kk2 < 2; ++kk2) {
            bf16x8 pf = *(const bf16x8*)&sPw[(lane & 15) * SVS + kk2 * 32 + (lane >> 4) * 8];
            #pragma unroll
            for (int j2 = 0; j2 < 8; ++j2) {
                bf16x8 vf = *(const bf16x8*)&sVT[(j2 * 16 + (lane & 15)) * SVS +
                                                 kk2 * 32 + (lane >> 4) * 8];
                o[j2] = mfma_bf16(pf, vf, o[j2]);
            }
        }
    }

    #pragma unroll
    for (int r = 0; r < 4; ++r) l_i[r] = redsum16(l_i[r]);
    #pragma unroll
    for (int j2 = 0; j2 < 8; ++j2)
        #pragma unroll
        for (int r = 0; r < 4; ++r) {
            int t   = qrow0 + (lane >> 4) * 4 + r;
            int col = head * 128 + j2 * 16 + (lane & 15);
            Y[(size_t)t * 4096 + col] = __float2bfloat16(o[j2][r] / l_i[r]);
        }
}

// ---------------------------------------------------------------------------
extern "C" void kernel_launch(void* const* d_in, const int* in_sizes, int n_in,
                              void* d_out, int out_size, void* d_ws, size_t ws_size,
                              hipStream_t stream) {
    const float* x    = (const float*)d_in[0];
    const float* cosp = (const float*)d_in[1];
    const float* sinp = (const float*)d_in[2];
    const float* wq   = (const float*)d_in[3];
    const float* wk   = (const float*)d_in[4];
    const float* wv   = (const float*)d_in[5];
    const float* wo   = (const float*)d_in[6];
    const int*   sp   = (const int*)d_in[7];
    float* out = (float*)d_out;

    char* ws = (char*)d_ws;
    bf16* Qb = (bf16*)d_out;   // 16 MB bf16 in the 32 MB f32 out buffer

    const size_t NEED = 92274688;   // 88 MiB
    if (ws_size >= NEED) {
        bf16* xb   = (bf16*)(ws);
        bf16* wqkv = (bf16*)(ws + (16u << 20));
        bf16* wob  = wqkv;                     // aliased; converted after QKV GEMM
        bf16* Kb   = (bf16*)(ws + (64u << 20));
        bf16* VT   = (bf16*)(ws + (68u << 20));
        bf16* Yb   = (bf16*)(ws + (72u << 20));

        cvt4_k<<<dim3(4096), 256, 0, stream>>>(x, xb, wq, wqkv,
                                               wk, wqkv + 16777216, wv, wqkv + 20971520);

        gemm_bt_p<2><<<dim3(48, 16), 256, 0, stream>>>(
            xb, wqkv, nullptr, Qb, Kb, VT, 2048, 6144, 4096);

        cvt_f32_bf16<<<dim3(4096), 256, 0, stream>>>(wo, wob, 2097152);

        rope_all<<<dim3(2048 * 40 * 64 / 256), 256, 0, stream>>>(Qb, Kb, cosp, sinp, sp);

        attn_k<<<dim3(1024), 256, 0, stream>>>(Qb, Kb, VT, Yb);

        gemm_bt_p<3><<<dim3(32, 16), 256, 0, stream>>>(
            Yb, wob, out, nullptr, nullptr, nullptr, 2048, 4096, 4096);
    } else {
        bf16* Kb = (bf16*)(ws);
        bf16* VT = (bf16*)(ws + (4u << 20));
        bf16* Yb = (bf16*)(ws + (8u << 20));

        gemm_bt<true, true, 0><<<dim3(32, 16), 256, 0, stream>>>(
            x, wq, Qb, nullptr, nullptr, nullptr, 2048, 4096, 4096);
        gemm_bt<true, true, 0><<<dim3(8, 16), 256, 0, stream>>>(
            x, wk, Kb, nullptr, nullptr, nullptr, 2048, 1024, 4096);
        gemm_bt<true, true, 1><<<dim3(8, 16), 256, 0, stream>>>(
            x, wv, VT, nullptr, nullptr, nullptr, 2048, 1024, 4096);

        rope_all<<<dim3(2048 * 40 * 64 / 256), 256, 0, stream>>>(Qb, Kb, cosp, sinp, sp);

        attn_k<<<dim3(1024), 256, 0, stream>>>(Qb, Kb, VT, Yb);

        gemm_bt<false, true, 3><<<dim3(32, 16), 256, 0, stream>>>(
            Yb, wo, out, nullptr, nullptr, nullptr, 2048, 4096, 4096);
    }
}